// Round 14
// baseline (445.749 us; speedup 1.0000x reference)
//
#include <hip/hip_runtime.h>
#include <hip/hip_bf16.h>

#define NB 32    // batch
#define CC 64    // channels
#define VV 500   // nodes
#define LL 64    // time length
#define EE 10    // embedding dim
#define CO 64    // out channels
#define DIL 2    // dilation / shift step
#define VP 512   // padded V for MFMA (k and m padded)
#define SL (VV * LL)   // 32000 flattened (v,l)

typedef unsigned short u16;
typedef unsigned int   u32;
typedef __attribute__((ext_vector_type(8))) short bf16x8;
typedef __attribute__((ext_vector_type(4))) float f32x4;

__device__ __forceinline__ float bf2f(u16 u) {
    union { u32 i; float f; } c; c.i = ((u32)u) << 16; return c.f;
}
__device__ __forceinline__ u16 f2bf(float f) {
    union { float f; u32 i; } c; c.f = f;
    u32 x = c.i;
    u32 r = (x + 0x7fffu + ((x >> 16) & 1u)) >> 16; // RNE
    return (u16)r;
}

// ---------------------------------------------------------------------------
// K0: embedding affine update + mlp_w -> bf16 conversion
// ---------------------------------------------------------------------------
__global__ void emb_kernel(const float* __restrict__ nv1, const float* __restrict__ nv2,
                           const float* __restrict__ et_w, const float* __restrict__ et_b,
                           const float* __restrict__ mlp_w,
                           float* __restrict__ nv1t, float* __restrict__ nv2t,
                           u16* __restrict__ wb) {
    int idx = blockIdx.x * blockDim.x + threadIdx.x;
    if (idx < VV * EE) {
        int v = idx / EE, e = idx - v * EE;
        float s = et_b[e];
        #pragma unroll
        for (int f = 0; f < EE; f++) s += nv1[v * EE + f] * et_w[f * EE + e];
        nv1t[idx] = s;
    } else if (idx < 2 * VV * EE) {
        int k = idx - VV * EE;
        int e = k / VV, v = k - e * VV;
        float s = et_b[e];
        #pragma unroll
        for (int f = 0; f < EE; f++) s += nv2[f * VV + v] * et_w[f * EE + e];
        nv2t[k] = s;
    } else if (idx < 2 * VV * EE + CO * 3 * CC) {
        int k = idx - 2 * VV * EE;
        wb[k] = f2bf(mlp_w[k]);
    }
}

// ---------------------------------------------------------------------------
// K1: both adjacencies in ONE launch (blocks 0..511 -> A0, 512..1023 -> A1).
// ---------------------------------------------------------------------------
__global__ __launch_bounds__(64) void adj2_kernel(const float* __restrict__ nv1,
                                                  const float* __restrict__ nv2,
                                                  const float* __restrict__ nv1t,
                                                  const float* __restrict__ nv2t,
                                                  u16* __restrict__ Atb0,
                                                  u16* __restrict__ Atb1) {
    const int which = blockIdx.x >> 9;          // 0 or 1
    const int v = blockIdx.x & (VP - 1);        // 0..511
    const float* p1 = which ? nv1t : nv1;
    const float* p2 = which ? nv2t : nv2;
    u16* Atb = which ? Atb1 : Atb0;
    const int lane = threadIdx.x;
    if (v >= VV) {
        #pragma unroll
        for (int j = 0; j < 8; j++) Atb[(size_t)(lane + 64 * j) * VP + v] = 0;
        return;
    }
    float e1[EE];
    #pragma unroll
    for (int e = 0; e < EE; e++) e1[e] = p1[v * EE + e];

    float r[8];
    float m = -1e30f;
    #pragma unroll
    for (int j = 0; j < 8; j++) {
        int w = lane + 64 * j;
        if (w < VV) {
            float s = 0.f;
            #pragma unroll
            for (int e = 0; e < EE; e++) s += e1[e] * p2[e * VV + w];
            r[j] = fmaxf(s, 0.f);
            m = fmaxf(m, r[j]);
        } else {
            r[j] = -1e30f;
        }
    }
    #pragma unroll
    for (int off = 32; off > 0; off >>= 1) m = fmaxf(m, __shfl_xor(m, off));

    float p[8];
    float sum = 0.f;
    #pragma unroll
    for (int j = 0; j < 8; j++) {
        int w = lane + 64 * j;
        if (w < VV) { p[j] = expf(r[j] - m); sum += p[j]; }
    }
    #pragma unroll
    for (int off = 32; off > 0; off >>= 1) sum += __shfl_xor(sum, off);
    float inv = 1.f / sum;
    #pragma unroll
    for (int j = 0; j < 8; j++) {
        int w = lane + 64 * j;
        Atb[(size_t)w * VP + v] = (w < VV) ? f2bf(p[j] * inv) : (u16)0;
    }
}

// ---------------------------------------------------------------------------
// K2: FUSED hops, DUAL-PLANE blocks. Block = 2 planes (2*bid, 2*bid+1).
// LDS: Xt[2][64 l][512 v] bf16 swizzled = 128 KB (1 block/CU, 2 waves/SIMD,
// VGPR cap 256). A-fragments straight from L2 (imm-offset loads, compiler-
// pipelined; ~200 free VGPRs of lookahead room). Each A-frag feeds 32 MFMA
// (both planes) -> 2x MFMA per fixed per-step overhead; kernel-level A
// re-read halves (1024 blocks). Fusion/staging/rewrite logic as before, x2.
// ---------------------------------------------------------------------------
__global__ __launch_bounds__(512, 2) void hops_fused(const float* __restrict__ x,
                                                     const u16* __restrict__ Atb0,
                                                     const u16* __restrict__ Atb1,
                                                     u16* __restrict__ x1g,
                                                     u16* __restrict__ x2g) {
    __shared__ u16 Xt[2][LL * VP];        // 2 x 64 KB
    const int bid = blockIdx.x;
    const int tid = threadIdx.x;
    const int lane = tid & 63;
    const int wv = tid >> 6;
    const int wr = wv * 64;
    const size_t base0 = (size_t)(2 * bid) * (VV * LL);
    const size_t base1 = base0 + (VV * LL);

    // ---- stage both planes (fp32 -> bf16, transpose, swizzled writes) ----
    {
        const int lquad = lane & 15;
        const int vsub = lane >> 4;
        const int l0 = 4 * lquad;
        #pragma unroll
        for (int pl = 0; pl < 2; ++pl) {
            char* ldsb = (char*)Xt[pl];
            const float* xp = x + (pl ? base1 : base0);
            #pragma unroll
            for (int i = 0; i < 8; ++i) {
                const int vp = wv * 32 + i * 4 + vsub;  // v-pair 0..255
                const int v0 = 2 * vp;
                u32 pk0, pk1, pk2, pk3;
                if (v0 < VV) {
                    const float* xa = xp + v0 * LL + l0;
                    float4 fa = *(const float4*)xa;
                    float4 fb = *(const float4*)(xa + LL);
                    pk0 = (u32)f2bf(fa.x) | ((u32)f2bf(fb.x) << 16);
                    pk1 = (u32)f2bf(fa.y) | ((u32)f2bf(fb.y) << 16);
                    pk2 = (u32)f2bf(fa.z) | ((u32)f2bf(fb.z) << 16);
                    pk3 = (u32)f2bf(fa.w) | ((u32)f2bf(fb.w) << 16);
                } else {
                    pk0 = pk1 = pk2 = pk3 = 0;
                }
                const int vb = 4 * vp;
                int l = l0;
                *(u32*)(ldsb + l * (VP * 2) + (vb ^ ((l & 7) << 4))) = pk0; l++;
                *(u32*)(ldsb + l * (VP * 2) + (vb ^ ((l & 7) << 4))) = pk1; l++;
                *(u32*)(ldsb + l * (VP * 2) + (vb ^ ((l & 7) << 4))) = pk2; l++;
                *(u32*)(ldsb + l * (VP * 2) + (vb ^ ((l & 7) << 4))) = pk3;
            }
        }
    }
    __syncthreads();

    // ---- compute geometry (thread-constant) ----
    const int r15 = lane & 15;
    const int kg = lane >> 4;
    const char* lds0 = (const char*)Xt[0];
    const char* lds1 = (const char*)Xt[1];
    int lrow[4], lswz[4];
    #pragma unroll
    for (int ct = 0; ct < 4; ct++) {
        const int l = ct * 16 + r15;
        lrow[ct] = l * (VP * 2);
        lswz[ct] = (l & 7) << 4;
    }
    const u16* arow0[4];
    const u16* arow1[4];
    #pragma unroll
    for (int rt = 0; rt < 4; rt++) {
        const size_t ro = (size_t)(wr + rt * 16 + r15) * VP + kg * 8;
        arow0[rt] = Atb0 + ro;
        arow1[rt] = Atb1 + ro;
    }

    f32x4 acc0[4][4], acc1[4][4];
    #pragma unroll
    for (int rt = 0; rt < 4; rt++)
        #pragma unroll
        for (int ct = 0; ct < 4; ct++) {
            acc0[rt][ct] = (f32x4){0.f, 0.f, 0.f, 0.f};
            acc1[rt][ct] = (f32x4){0.f, 0.f, 0.f, 0.f};
        }

    // ==================== hop 0 ====================
    #pragma unroll
    for (int kb = 0; kb < VP; kb += 32) {
        bf16x8 a[4], b0[4], b1[4];
        #pragma unroll
        for (int rt = 0; rt < 4; rt++)
            a[rt] = *(const bf16x8*)(arow0[rt] + kb);
        #pragma unroll
        for (int ct = 0; ct < 4; ct++) {
            const int ko = (kb * 2 + kg * 16) ^ lswz[ct];
            b0[ct] = *(const bf16x8*)(lds0 + lrow[ct] + ko);
            b1[ct] = *(const bf16x8*)(lds1 + lrow[ct] + ko);
        }
        __builtin_amdgcn_s_setprio(1);
        #pragma unroll
        for (int rt = 0; rt < 4; rt++)
            #pragma unroll
            for (int ct = 0; ct < 4; ct++) {
                acc0[rt][ct] = __builtin_amdgcn_mfma_f32_16x16x32_bf16(a[rt], b0[ct], acc0[rt][ct], 0, 0, 0);
                acc1[rt][ct] = __builtin_amdgcn_mfma_f32_16x16x32_bf16(a[rt], b1[ct], acc1[rt][ct], 0, 0, 0);
            }
        __builtin_amdgcn_s_setprio(0);
    }

    // ---- store x1 (both planes, unshifted) ----
    #pragma unroll
    for (int pl = 0; pl < 2; ++pl) {
        u16* xo = x1g + (pl ? base1 : base0);
        #pragma unroll
        for (int rt = 0; rt < 4; rt++) {
            #pragma unroll
            for (int ct = 0; ct < 4; ct++) {
                const int col = ct * 16 + r15;
                const int wbase = wr + rt * 16 + kg * 4;
                f32x4 c = pl ? acc1[rt][ct] : acc0[rt][ct];
                #pragma unroll
                for (int r = 0; r < 4; r++) {
                    int w = wbase + r;
                    if (w < VV) xo[w * LL + col] = f2bf(c[r]);
                }
            }
        }
    }
    __syncthreads();   // all waves done reading Xt for hop0

    // ---- rewrite Xt[pl][l][v] = x1_pl[v][l-DIL], rows l<DIL zeroed ----
    {
        #pragma unroll
        for (int pl = 0; pl < 2; ++pl) {
            char* ldsw = (char*)Xt[pl];
            {
                const int l = tid >> 8;          // 0..1 (DIL==2)
                const int j = tid & 255;
                *(u32*)(ldsw + l * (VP * 2) + 4 * j) = 0;
            }
            #pragma unroll
            for (int rt = 0; rt < 4; rt++) {
                const int wb2 = (wr + rt * 16 + kg * 4) * 2;
                #pragma unroll
                for (int ct = 0; ct < 4; ct++) {
                    const int col = ct * 16 + r15;
                    const int ln = col + DIL;
                    if (ln < LL) {
                        f32x4 c = pl ? acc1[rt][ct] : acc0[rt][ct];
                        u32 plo = (u32)f2bf(c[0]) | ((u32)f2bf(c[1]) << 16);
                        u32 phi = (u32)f2bf(c[2]) | ((u32)f2bf(c[3]) << 16);
                        const int swz = (ln & 7) << 4;
                        char* p = ldsw + ln * (VP * 2);
                        *(u32*)(p + (wb2 ^ swz)) = plo;
                        *(u32*)(p + ((wb2 + 4) ^ swz)) = phi;
                    }
                }
            }
        }
    }
    __syncthreads();

    #pragma unroll
    for (int rt = 0; rt < 4; rt++)
        #pragma unroll
        for (int ct = 0; ct < 4; ct++) {
            acc0[rt][ct] = (f32x4){0.f, 0.f, 0.f, 0.f};
            acc1[rt][ct] = (f32x4){0.f, 0.f, 0.f, 0.f};
        }

    // ==================== hop 1 ====================
    #pragma unroll
    for (int kb = 0; kb < VP; kb += 32) {
        bf16x8 a[4], b0[4], b1[4];
        #pragma unroll
        for (int rt = 0; rt < 4; rt++)
            a[rt] = *(const bf16x8*)(arow1[rt] + kb);
        #pragma unroll
        for (int ct = 0; ct < 4; ct++) {
            const int ko = (kb * 2 + kg * 16) ^ lswz[ct];
            b0[ct] = *(const bf16x8*)(lds0 + lrow[ct] + ko);
            b1[ct] = *(const bf16x8*)(lds1 + lrow[ct] + ko);
        }
        __builtin_amdgcn_s_setprio(1);
        #pragma unroll
        for (int rt = 0; rt < 4; rt++)
            #pragma unroll
            for (int ct = 0; ct < 4; ct++) {
                acc0[rt][ct] = __builtin_amdgcn_mfma_f32_16x16x32_bf16(a[rt], b0[ct], acc0[rt][ct], 0, 0, 0);
                acc1[rt][ct] = __builtin_amdgcn_mfma_f32_16x16x32_bf16(a[rt], b1[ct], acc1[rt][ct], 0, 0, 0);
            }
        __builtin_amdgcn_s_setprio(0);
    }

    // ---- store x2 (both planes) ----
    #pragma unroll
    for (int pl = 0; pl < 2; ++pl) {
        u16* xo = x2g + (pl ? base1 : base0);
        #pragma unroll
        for (int rt = 0; rt < 4; rt++) {
            #pragma unroll
            for (int ct = 0; ct < 4; ct++) {
                const int col = ct * 16 + r15;
                const int wbase = wr + rt * 16 + kg * 4;
                f32x4 c = pl ? acc1[rt][ct] : acc0[rt][ct];
                #pragma unroll
                for (int r = 0; r < 4; r++) {
                    int w = wbase + r;
                    if (w < VV) xo[w * LL + col] = f2bf(c[r]);
                }
            }
        }
    }
}

// ---------------------------------------------------------------------------
// K3: MLP via MFMA (unchanged — near HBM floor).
// ---------------------------------------------------------------------------
__global__ __launch_bounds__(256, 3) void mlp_mfma(const float* __restrict__ x,
                                                   const u16* __restrict__ x1,
                                                   const u16* __restrict__ x2,
                                                   const u16* __restrict__ wb,
                                                   const float* __restrict__ b,
                                                   float* __restrict__ out) {
    __shared__ u16 Ht[128 * 192];   // 49152 B
    const int bid = blockIdx.x;
    const int n = bid / (SL / 128);
    const int st = bid - n * (SL / 128);
    const int s0 = st * 128;
    const int tid = threadIdx.x;

    const int lane = tid & 63;
    const int wv = tid >> 6;
    const int obase = (wv & 1) * 32;
    const int sbase = (wv >> 1) * 64;
    const int r15 = lane & 15;
    const int kg = lane >> 4;

    bf16x8 afrag[2][6];
    #pragma unroll
    for (int rt = 0; rt < 2; rt++)
        #pragma unroll
        for (int ks = 0; ks < 6; ks++)
            afrag[rt][ks] = *(const bf16x8*)(wb + (obase + rt * 16 + r15) * (3 * CC) + ks * 32 + kg * 8);

    {
        char* ldsb = (char*)Ht;
        const int squad = tid >> 3;
        const int pgroup = tid & 7;
        const int sq0 = 4 * squad;
        #pragma unroll
        for (int i = 0; i < 12; ++i) {
            const int P = i * 8 + pgroup;
            const int c = 2 * P;
            u32 pk0, pk1, pk2, pk3;
            if (i < 4) {
                const float* fsrc = x + ((size_t)n * CC + c) * SL + s0 + sq0;
                float4 va = *(const float4*)fsrc;
                float4 vb = *(const float4*)(fsrc + SL);
                pk0 = (u32)f2bf(va.x) | ((u32)f2bf(vb.x) << 16);
                pk1 = (u32)f2bf(va.y) | ((u32)f2bf(vb.y) << 16);
                pk2 = (u32)f2bf(va.z) | ((u32)f2bf(vb.z) << 16);
                pk3 = (u32)f2bf(va.w) | ((u32)f2bf(vb.w) << 16);
            } else {
                const u16* bsrc = (i < 8)
                    ? x1 + ((size_t)n * CC + (c - CC)) * SL + s0 + sq0
                    : x2 + ((size_t)n * CC + (c - 2 * CC)) * SL + s0 + sq0;
                uint2 va = *(const uint2*)bsrc;
                uint2 vb = *(const uint2*)(bsrc + SL);
                pk0 = (va.x & 0xffffu) | (vb.x << 16);
                pk1 = (va.x >> 16) | (vb.x & 0xffff0000u);
                pk2 = (va.y & 0xffffu) | (vb.y << 16);
                pk3 = (va.y >> 16) | (vb.y & 0xffff0000u);
            }
            int s = sq0;
            *(u32*)(ldsb + s * 384 + ((4 * P) ^ ((s & 7) << 4))) = pk0; s++;
            *(u32*)(ldsb + s * 384 + ((4 * P) ^ ((s & 7) << 4))) = pk1; s++;
            *(u32*)(ldsb + s * 384 + ((4 * P) ^ ((s & 7) << 4))) = pk2; s++;
            *(u32*)(ldsb + s * 384 + ((4 * P) ^ ((s & 7) << 4))) = pk3;
        }
    }
    __syncthreads();

    f32x4 acc[2][4];
    #pragma unroll
    for (int rt = 0; rt < 2; rt++)
        #pragma unroll
        for (int ct = 0; ct < 4; ct++)
            acc[rt][ct] = (f32x4){0.f, 0.f, 0.f, 0.f};

    const char* ldsb = (const char*)Ht;
    #pragma unroll
    for (int ks = 0; ks < 6; ks++) {
        bf16x8 bfr[4];
        #pragma unroll
        for (int ct = 0; ct < 4; ct++) {
            const int s = sbase + ct * 16 + r15;
            bfr[ct] = *(const bf16x8*)(ldsb + s * 384 + ((ks * 64 + kg * 16) ^ ((s & 7) << 4)));
        }
        #pragma unroll
        for (int rt = 0; rt < 2; rt++)
            #pragma unroll
            for (int ct = 0; ct < 4; ct++)
                acc[rt][ct] = __builtin_amdgcn_mfma_f32_16x16x32_bf16(afrag[rt][ks], bfr[ct], acc[rt][ct], 0, 0, 0);
    }

    #pragma unroll
    for (int rt = 0; rt < 2; rt++) {
        #pragma unroll
        for (int r = 0; r < 4; r++) {
            const int o = obase + rt * 16 + kg * 4 + r;
            const float bias = b[o];
            float* orow = out + ((size_t)n * CO + o) * SL + s0 + sbase;
            #pragma unroll
            for (int ct = 0; ct < 4; ct++)
                orow[ct * 16 + r15] = acc[rt][ct][r] + bias;
        }
    }
}

// ---------------------------------------------------------------------------
extern "C" void kernel_launch(void* const* d_in, const int* in_sizes, int n_in,
                              void* d_out, int out_size, void* d_ws, size_t ws_size,
                              hipStream_t stream) {
    const float* x     = (const float*)d_in[0];
    const float* nv1   = (const float*)d_in[1];
    const float* nv2   = (const float*)d_in[2];
    const float* et_w  = (const float*)d_in[3];
    const float* et_b  = (const float*)d_in[4];
    const float* mlp_w = (const float*)d_in[5];
    const float* mlp_b = (const float*)d_in[6];
    float* out = (float*)d_out;

    char* wsb = (char*)d_ws;
    size_t off = 0;
    auto alloc = [&](size_t bytes) {
        size_t o = off;
        off += (bytes + 255) & ~(size_t)255;
        return o;
    };
    u16*   Atb0 = (u16*)(wsb + alloc((size_t)VP * VP * 2));
    u16*   Atb1 = (u16*)(wsb + alloc((size_t)VP * VP * 2));
    float* nv1t = (float*)(wsb + alloc((size_t)VV * EE * 4));
    float* nv2t = (float*)(wsb + alloc((size_t)EE * VV * 4));
    u16*   wb   = (u16*)(wsb + alloc((size_t)CO * 3 * CC * 2));
    u16*   x1   = (u16*)(wsb + alloc((size_t)NB * CC * VV * LL * 2));
    u16*   x2   = (u16*)(wsb + alloc((size_t)NB * CC * VV * LL * 2));
    (void)in_sizes; (void)n_in; (void)out_size; (void)ws_size;

    const int embN = 2 * VV * EE + CO * 3 * CC;
    emb_kernel<<<(embN + 255) / 256, 256, 0, stream>>>(nv1, nv2, et_w, et_b, mlp_w, nv1t, nv2t, wb);
    adj2_kernel<<<2 * VP, 64, 0, stream>>>(nv1, nv2, nv1t, nv2t, Atb0, Atb1);
    hops_fused<<<NB * CC / 2, 512, 0, stream>>>(x, Atb0, Atb1, x1, x2);
    mlp_mfma<<<NB * (SL / 128), 256, 0, stream>>>(x, x1, x2, wb, mlp_b, out);
}